// Round 9
// baseline (397.586 us; speedup 1.0000x reference)
//
#include <hip/hip_runtime.h>
#include <cstdint>

#define ALPHA 0.2f

constexpr int NB = 8;
constexpr int NN = 2048;
constexpr int NF = 256;

typedef __attribute__((ext_vector_type(8))) short bf16x8;
typedef __attribute__((ext_vector_type(4))) float f32x4;

__device__ __forceinline__ float bf2f(unsigned short u) {
    union { unsigned int i; float f; } v;
    v.i = ((unsigned int)u) << 16;
    return v.f;
}
__device__ __forceinline__ unsigned short f2bf(float f) {
    union { float f; unsigned int i; } v;
    v.f = f;
    v.i += 0x7fffu + ((v.i >> 16) & 1);  // round-to-nearest-even
    return (unsigned short)(v.i >> 16);
}

// ---------------------------------------------------------------------------
// Kernel 0: WT[f][k] = bf16(W[k][f])  (256x256, one-shot transpose+cast)
// ---------------------------------------------------------------------------
__global__ __launch_bounds__(256) void k_wt(const float* __restrict__ W,
                                            unsigned short* __restrict__ WT) {
    const int t = threadIdx.x;
    const int k = blockIdx.x * 4 + (t >> 6);
    const int f0 = (t & 63) * 4;
    const float4 w = *(const float4*)&W[k * NF + f0];
    WT[(f0 + 0) * NF + k] = f2bf(w.x);
    WT[(f0 + 1) * NF + k] = f2bf(w.y);
    WT[(f0 + 2) * NF + k] = f2bf(w.z);
    WT[(f0 + 3) * NF + k] = f2bf(w.w);
}

// ---------------------------------------------------------------------------
// Kernel 1: WhT = (h @ W)^T per batch, bf16 MFMA.
// 64x64 tile/block, 4 waves each 32x32 (2x2 frags of 16x16x32), K chunks of 64.
// h cast fp32->bf16 at staging; B-operand from pre-transposed WT (k-contig).
// Store directly into WhT[b][f][n] (C-layout rows are n-contiguous per lane).
// ---------------------------------------------------------------------------
__global__ __launch_bounds__(256, 4) void k_wh(const float* __restrict__ h,
                                               const unsigned short* __restrict__ WT,
                                               unsigned short* __restrict__ WhT) {
    __shared__ __align__(16) unsigned short As[64][72];  // [row][k] bf16
    __shared__ __align__(16) unsigned short Bs[64][72];  // [f][k]  bf16
    const int tid = threadIdx.x;
    const int lane = tid & 63;
    const int l16 = lane & 15;
    const int quad = lane >> 4;
    const int wave = tid >> 6;
    const int row0 = (blockIdx.x >> 2) * 64;  // global node-row, 64-mult
    const int col0 = (blockIdx.x & 3) * 64;   // f
    const int bb = row0 >> 11;
    const int n0 = row0 & (NN - 1);
    const int mb = (wave & 1) * 32;   // node sub-tile
    const int nb = (wave >> 1) * 32;  // f sub-tile

    f32x4 acc[2][2];
#pragma unroll
    for (int mf = 0; mf < 2; ++mf)
#pragma unroll
        for (int nf = 0; nf < 2; ++nf) acc[mf][nf] = (f32x4){0.f, 0.f, 0.f, 0.f};

    for (int k0 = 0; k0 < NF; k0 += 64) {
        // stage A: 64 rows x 64 k, fp32 -> bf16
#pragma unroll
        for (int it = 0; it < 4; ++it) {
            const int q = tid + it * 256;   // 0..1023
            const int r = q >> 4;           // 0..63
            const int k4 = (q & 15) * 4;    // 0..60
            const float4 v = *(const float4*)&h[(size_t)(row0 + r) * NF + k0 + k4];
            ushort4 o;
            o.x = f2bf(v.x); o.y = f2bf(v.y); o.z = f2bf(v.z); o.w = f2bf(v.w);
            *(ushort4*)&As[r][k4] = o;
        }
        // stage B: 64 f x 64 k bf16 from WT (contiguous uint4)
#pragma unroll
        for (int it = 0; it < 2; ++it) {
            const int q = tid + it * 256;   // 0..511
            const int f = q >> 3;           // 0..63
            const int k8 = (q & 7) * 8;     // 0..56
            *(uint4*)&Bs[f][k8] =
                *(const uint4*)&WT[(size_t)(col0 + f) * NF + k0 + k8];
        }
        __syncthreads();
#pragma unroll
        for (int ks = 0; ks < 64; ks += 32) {
            bf16x8 a[2], b[2];
#pragma unroll
            for (int mf = 0; mf < 2; ++mf)
                a[mf] = *(const bf16x8*)&As[mb + mf * 16 + l16][ks + quad * 8];
#pragma unroll
            for (int nf = 0; nf < 2; ++nf)
                b[nf] = *(const bf16x8*)&Bs[nb + nf * 16 + l16][ks + quad * 8];
#pragma unroll
            for (int mf = 0; mf < 2; ++mf)
#pragma unroll
                for (int nf = 0; nf < 2; ++nf)
                    acc[mf][nf] = __builtin_amdgcn_mfma_f32_16x16x32_bf16(
                        a[mf], b[nf], acc[mf][nf], 0, 0, 0);
        }
        __syncthreads();
    }
    // store: lane holds (n = quad*4+reg, f = l16) per frag -> ushort4 along n
#pragma unroll
    for (int mf = 0; mf < 2; ++mf) {
#pragma unroll
        for (int nf = 0; nf < 2; ++nf) {
            const size_t f = col0 + nb + nf * 16 + l16;
            const int nr = n0 + mb + mf * 16 + quad * 4;
            ushort4 o;
            o.x = f2bf(acc[mf][nf][0]);
            o.y = f2bf(acc[mf][nf][1]);
            o.z = f2bf(acc[mf][nf][2]);
            o.w = f2bf(acc[mf][nf][3]);
            *(ushort4*)&WhT[((size_t)bb * NF + f) * NN + nr] = o;
        }
    }
}

// ---------------------------------------------------------------------------
// Kernel S: s1[n] = sum_f WhT[b][f][n]*a1[f]; s2 likewise. Coalesced along n.
// ---------------------------------------------------------------------------
__global__ __launch_bounds__(256) void k_s12(const unsigned short* __restrict__ WhT,
                                             const float* __restrict__ a,
                                             float* __restrict__ s1,
                                             float* __restrict__ s2) {
    const int tid = threadIdx.x;
    const int bb = blockIdx.x >> 3;
    const int n = (blockIdx.x & 7) * 256 + tid;
    const unsigned short* base = WhT + (size_t)bb * NF * NN + n;
    float s1v = 0.f, s2v = 0.f;
#pragma unroll 4
    for (int f = 0; f < NF; ++f) {
        const float v = bf2f(base[(size_t)f * NN]);
        s1v += v * a[f];
        s2v += v * a[NF + f];
    }
    s1[bb * NN + n] = s1v;
    s2[bb * NN + n] = s2v;
}

// ---------------------------------------------------------------------------
// Kernel 2: fused masked softmax + attn @ Wh, MFMA + register-prefetch
// pipeline. Block = 32 q-rows x 256 f; grid 512 (2 blocks/CU).
// Per j-tile of 64: [write prefetched regs->LDS, P from regs, bar,
// issue t+1 loads, MFMA, bar]. t+1 global loads fly during MFMA+barrier.
// ---------------------------------------------------------------------------
__global__ __launch_bounds__(256, 2) void k_attn(const unsigned short* __restrict__ WhT,
                                                 const int* __restrict__ adj,
                                                 const float* __restrict__ s1g,
                                                 const float* __restrict__ s2g,
                                                 float* __restrict__ out) {
    __shared__ __align__(16) unsigned short WhsT[256][72];  // [f][k]
    __shared__ __align__(16) unsigned short Pb[32][72];     // [i][k]
    __shared__ float s1_s[32];
    __shared__ float l_s[32];

    const int tid = threadIdx.x;
    const int lane = tid & 63;
    const int l16 = lane & 15;
    const int quad = lane >> 4;
    const int wave = tid >> 6;
    const int bb = blockIdx.x >> 6;
    const int i0 = (blockIdx.x & 63) * 32;

    if (tid < 32) {
        s1_s[tid] = s1g[bb * NN + i0 + tid];
        l_s[tid] = 0.f;
    }
    __syncthreads();

    f32x4 acc[2][4];
#pragma unroll
    for (int m = 0; m < 2; ++m)
#pragma unroll
        for (int nf = 0; nf < 4; ++nf) acc[m][nf] = (f32x4){0.f, 0.f, 0.f, 0.f};

    const size_t whtBase = (size_t)bb * NF * NN;
    const size_t adjBase = (size_t)bb * NN * NN;
    const float* s2b = s2g + bb * NN;

    uint4 whReg[8];
    int4 adjReg[2];
    float4 s2Reg[2];

    auto load_tile = [&](int jt) {
        const int j0 = jt * 64;
#pragma unroll
        for (int it = 0; it < 8; ++it) {
            const int q = tid + it * 256;
            const int f = q >> 3;
            const int kc = (q & 7) * 8;
            whReg[it] = *(const uint4*)&WhT[whtBase + (size_t)f * NN + j0 + kc];
        }
#pragma unroll
        for (int it = 0; it < 2; ++it) {
            const int q = tid + it * 256;       // 0..511
            const int ir = q >> 4;              // 0..31
            const int kq = (q & 15) * 4;        // 0..60
            adjReg[it] = *(const int4*)&adj[adjBase + (size_t)(i0 + ir) * NN + j0 + kq];
            s2Reg[it] = *(const float4*)&s2b[j0 + kq];
        }
    };

    load_tile(0);  // prologue prefetch

    for (int t = 0; t < NN / 64; ++t) {
        // ---- prefetched WhT regs -> LDS ----
#pragma unroll
        for (int it = 0; it < 8; ++it) {
            const int q = tid + it * 256;
            const int f = q >> 3;
            const int kc = (q & 7) * 8;
            *(uint4*)&WhsT[f][kc] = whReg[it];
        }
        // ---- P from regs: 4 j per thread x 2 iters ----
#pragma unroll
        for (int it = 0; it < 2; ++it) {
            const int q = tid + it * 256;
            const int ir = q >> 4;
            const int kq = (q & 15) * 4;
            const int4 av = adjReg[it];
            const float4 s2v = s2Reg[it];
            const float s1v = s1_s[ir];
            float x0 = s1v + s2v.x, x1 = s1v + s2v.y;
            float x2 = s1v + s2v.z, x3 = s1v + s2v.w;
            x0 = x0 > 0.f ? x0 : ALPHA * x0;
            x1 = x1 > 0.f ? x1 : ALPHA * x1;
            x2 = x2 > 0.f ? x2 : ALPHA * x2;
            x3 = x3 > 0.f ? x3 : ALPHA * x3;
            const float p0 = av.x > 0 ? __expf(x0) : 0.f;
            const float p1 = av.y > 0 ? __expf(x1) : 0.f;
            const float p2 = av.z > 0 ? __expf(x2) : 0.f;
            const float p3 = av.w > 0 ? __expf(x3) : 0.f;
            uint2 pk;
            pk.x = (unsigned int)f2bf(p0) | ((unsigned int)f2bf(p1) << 16);
            pk.y = (unsigned int)f2bf(p2) | ((unsigned int)f2bf(p3) << 16);
            *(uint2*)&Pb[ir][kq] = pk;
            float ps = (p0 + p1) + (p2 + p3);
            ps += __shfl_xor(ps, 8);
            ps += __shfl_xor(ps, 4);
            ps += __shfl_xor(ps, 2);
            ps += __shfl_xor(ps, 1);
            if ((tid & 15) == 0) l_s[ir] += ps;  // unique thread per ir
        }
        __syncthreads();
        // ---- issue next tile's global loads (regs only; overlap MFMA) ----
        if (t + 1 < NN / 64) load_tile(t + 1);
        // ---- MFMA: out[32 x 64f] += P[32 x 64k] * WhsT[64k x 64f]^T ----
        const int f0 = wave * 64;
#pragma unroll
        for (int k0 = 0; k0 < 64; k0 += 32) {
            bf16x8 af[2];
#pragma unroll
            for (int m = 0; m < 2; ++m)
                af[m] = *(const bf16x8*)&Pb[m * 16 + l16][k0 + quad * 8];
#pragma unroll
            for (int nf = 0; nf < 4; ++nf) {
                const bf16x8 bfr =
                    *(const bf16x8*)&WhsT[f0 + nf * 16 + l16][k0 + quad * 8];
#pragma unroll
                for (int m = 0; m < 2; ++m)
                    acc[m][nf] = __builtin_amdgcn_mfma_f32_16x16x32_bf16(
                        af[m], bfr, acc[m][nf], 0, 0, 0);
            }
        }
        __syncthreads();
    }

    // ---- epilogue ----
    if (tid < 32) l_s[tid] = 1.0f / l_s[tid];
    __syncthreads();

    const int f0 = wave * 64;
#pragma unroll
    for (int m = 0; m < 2; ++m) {
#pragma unroll
        for (int r = 0; r < 4; ++r) {
            const int row = m * 16 + quad * 4 + r;
            const float inv = l_s[row];
#pragma unroll
            for (int nf = 0; nf < 4; ++nf) {
                out[((size_t)bb * NN + i0 + row) * NF + f0 + nf * 16 + l16] =
                    acc[m][nf][r] * inv;
            }
        }
    }
}

// ---------------------------------------------------------------------------
extern "C" void kernel_launch(void* const* d_in, const int* in_sizes, int n_in,
                              void* d_out, int out_size, void* d_ws, size_t ws_size,
                              hipStream_t stream) {
    const float* h = (const float*)d_in[0];
    const int* adj = (const int*)d_in[1];
    const float* W = (const float*)d_in[2];
    const float* a = (const float*)d_in[3];
    float* out = (float*)d_out;

    unsigned short* WhT = (unsigned short*)d_ws;  // 8.4 MB bf16, [b][f][n]
    float* s1 = (float*)((char*)d_ws + (size_t)NB * NN * NF * sizeof(unsigned short));
    float* s2 = s1 + (size_t)NB * NN;
    unsigned short* WT = (unsigned short*)(s2 + (size_t)NB * NN);  // 128 KB

    k_wt<<<dim3(64), dim3(256), 0, stream>>>(W, WT);
    k_wh<<<dim3((NB * NN / 64) * (NF / 64)), dim3(256), 0, stream>>>(h, WT, WhT);
    k_s12<<<dim3(NB * 8), dim3(256), 0, stream>>>(WhT, a, s1, s2);
    k_attn<<<dim3(NB * (NN / 32)), dim3(256), 0, stream>>>(WhT, adj, s1, s2, out);
}

// Round 10
// 239.163 us; speedup vs baseline: 1.6624x; 1.6624x over previous
//
#include <hip/hip_runtime.h>
#include <cstdint>

#define ALPHA 0.2f

constexpr int NB = 8;
constexpr int NN = 2048;
constexpr int NF = 256;

typedef __attribute__((ext_vector_type(8))) short bf16x8;
typedef __attribute__((ext_vector_type(4))) float f32x4;

__device__ __forceinline__ float bf2f(unsigned short u) {
    union { unsigned int i; float f; } v;
    v.i = ((unsigned int)u) << 16;
    return v.f;
}
__device__ __forceinline__ unsigned short f2bf(float f) {
    union { float f; unsigned int i; } v;
    v.f = f;
    v.i += 0x7fffu + ((v.i >> 16) & 1);  // round-to-nearest-even
    return (unsigned short)(v.i >> 16);
}

// ---------------------------------------------------------------------------
// Kernel 0: WT[f][k] = bf16(W[k][f]) transpose+cast; also zero s1/s2
// (grid 64 x 256 = 16384 threads = NB*NN exactly).
// ---------------------------------------------------------------------------
__global__ __launch_bounds__(256) void k_wt(const float* __restrict__ W,
                                            unsigned short* __restrict__ WT,
                                            float* __restrict__ s1,
                                            float* __restrict__ s2) {
    const int t = threadIdx.x;
    const int gid = blockIdx.x * 256 + t;
    s1[gid] = 0.f;
    s2[gid] = 0.f;
    const int k = blockIdx.x * 4 + (t >> 6);
    const int f0 = (t & 63) * 4;
    const float4 w = *(const float4*)&W[k * NF + f0];
    WT[(f0 + 0) * NF + k] = f2bf(w.x);
    WT[(f0 + 1) * NF + k] = f2bf(w.y);
    WT[(f0 + 2) * NF + k] = f2bf(w.z);
    WT[(f0 + 3) * NF + k] = f2bf(w.w);
}

// ---------------------------------------------------------------------------
// Kernel 1: WhT = (h @ W)^T per batch, bf16 MFMA; fused s1/s2 epilogue.
// 64x64 tile/block, 4 waves each 32x32 (2x2 frags of 16x16x32), K chunks 64.
// s1/s2: per-lane acc . a1/a2 partials, 16-lane shuffle reduce, atomicAdd.
// ---------------------------------------------------------------------------
__global__ __launch_bounds__(256, 4) void k_wh(const float* __restrict__ h,
                                               const unsigned short* __restrict__ WT,
                                               const float* __restrict__ a,
                                               unsigned short* __restrict__ WhT,
                                               float* __restrict__ s1,
                                               float* __restrict__ s2) {
    __shared__ __align__(16) unsigned short As[64][72];  // [row][k] bf16
    __shared__ __align__(16) unsigned short Bs[64][72];  // [f][k]  bf16
    const int tid = threadIdx.x;
    const int lane = tid & 63;
    const int l16 = lane & 15;
    const int quad = lane >> 4;
    const int wave = tid >> 6;
    const int row0 = (blockIdx.x >> 2) * 64;
    const int col0 = (blockIdx.x & 3) * 64;
    const int bb = row0 >> 11;
    const int n0 = row0 & (NN - 1);
    const int mb = (wave & 1) * 32;
    const int nb = (wave >> 1) * 32;

    f32x4 acc[2][2];
#pragma unroll
    for (int mf = 0; mf < 2; ++mf)
#pragma unroll
        for (int nf = 0; nf < 2; ++nf) acc[mf][nf] = (f32x4){0.f, 0.f, 0.f, 0.f};

    for (int k0 = 0; k0 < NF; k0 += 64) {
#pragma unroll
        for (int it = 0; it < 4; ++it) {
            const int q = tid + it * 256;
            const int r = q >> 4;
            const int k4 = (q & 15) * 4;
            const float4 v = *(const float4*)&h[(size_t)(row0 + r) * NF + k0 + k4];
            ushort4 o;
            o.x = f2bf(v.x); o.y = f2bf(v.y); o.z = f2bf(v.z); o.w = f2bf(v.w);
            *(ushort4*)&As[r][k4] = o;
        }
#pragma unroll
        for (int it = 0; it < 2; ++it) {
            const int q = tid + it * 256;
            const int f = q >> 3;
            const int k8 = (q & 7) * 8;
            *(uint4*)&Bs[f][k8] =
                *(const uint4*)&WT[(size_t)(col0 + f) * NF + k0 + k8];
        }
        __syncthreads();
#pragma unroll
        for (int ks = 0; ks < 64; ks += 32) {
            bf16x8 av[2], bv[2];
#pragma unroll
            for (int mf = 0; mf < 2; ++mf)
                av[mf] = *(const bf16x8*)&As[mb + mf * 16 + l16][ks + quad * 8];
#pragma unroll
            for (int nf = 0; nf < 2; ++nf)
                bv[nf] = *(const bf16x8*)&Bs[nb + nf * 16 + l16][ks + quad * 8];
#pragma unroll
            for (int mf = 0; mf < 2; ++mf)
#pragma unroll
                for (int nf = 0; nf < 2; ++nf)
                    acc[mf][nf] = __builtin_amdgcn_mfma_f32_16x16x32_bf16(
                        av[mf], bv[nf], acc[mf][nf], 0, 0, 0);
        }
        __syncthreads();
    }

    // ---- store WhT (C-layout: n = quad*4+reg contiguous per lane) ----
#pragma unroll
    for (int mf = 0; mf < 2; ++mf) {
#pragma unroll
        for (int nf = 0; nf < 2; ++nf) {
            const size_t f = col0 + nb + nf * 16 + l16;
            const int nr = n0 + mb + mf * 16 + quad * 4;
            ushort4 o;
            o.x = f2bf(acc[mf][nf][0]);
            o.y = f2bf(acc[mf][nf][1]);
            o.z = f2bf(acc[mf][nf][2]);
            o.w = f2bf(acc[mf][nf][3]);
            *(ushort4*)&WhT[((size_t)bb * NF + f) * NN + nr] = o;
        }
    }

    // ---- fused s1/s2 partials ----
    float a1v[2], a2v[2];
#pragma unroll
    for (int nf = 0; nf < 2; ++nf) {
        const int f = col0 + nb + nf * 16 + l16;
        a1v[nf] = a[f];
        a2v[nf] = a[NF + f];
    }
#pragma unroll
    for (int mf = 0; mf < 2; ++mf) {
#pragma unroll
        for (int r = 0; r < 4; ++r) {
            float p1 = acc[mf][0][r] * a1v[0] + acc[mf][1][r] * a1v[1];
            float p2 = acc[mf][0][r] * a2v[0] + acc[mf][1][r] * a2v[1];
            p1 += __shfl_xor(p1, 1); p2 += __shfl_xor(p2, 1);
            p1 += __shfl_xor(p1, 2); p2 += __shfl_xor(p2, 2);
            p1 += __shfl_xor(p1, 4); p2 += __shfl_xor(p2, 4);
            p1 += __shfl_xor(p1, 8); p2 += __shfl_xor(p2, 8);
            if (l16 == 0) {
                const int n = n0 + mb + mf * 16 + quad * 4 + r;
                atomicAdd(&s1[bb * NN + n], p1);
                atomicAdd(&s2[bb * NN + n], p2);
            }
        }
    }
}

// ---------------------------------------------------------------------------
// Kernel 2: fused masked softmax + attn @ Wh, MFMA + TRUE register prefetch
// (named scalar vars -> guaranteed VGPRs; no arrays/lambdas = no SROA fail).
// Block = 32 q-rows x 256 f; grid 512; 3 blocks/CU (LDS 42 KB).
// ---------------------------------------------------------------------------
__global__ __launch_bounds__(256, 3) void k_attn(const unsigned short* __restrict__ WhT,
                                                 const int* __restrict__ adj,
                                                 const float* __restrict__ s1g,
                                                 const float* __restrict__ s2g,
                                                 float* __restrict__ out) {
    __shared__ __align__(16) unsigned short WhsT[256][72];  // [f][k]
    __shared__ __align__(16) unsigned short Pb[32][72];     // [i][k]
    __shared__ float s1_s[32];
    __shared__ float l_s[32];

    const int tid = threadIdx.x;
    const int lane = tid & 63;
    const int l16 = lane & 15;
    const int quad = lane >> 4;
    const int wave = tid >> 6;
    const int bb = blockIdx.x >> 6;
    const int i0 = (blockIdx.x & 63) * 32;

    if (tid < 32) {
        s1_s[tid] = s1g[bb * NN + i0 + tid];
        l_s[tid] = 0.f;
    }
    __syncthreads();

    f32x4 acc[2][4];
#pragma unroll
    for (int m = 0; m < 2; ++m)
#pragma unroll
        for (int nf = 0; nf < 4; ++nf) acc[m][nf] = (f32x4){0.f, 0.f, 0.f, 0.f};

    const size_t whtBase = (size_t)bb * NF * NN;
    const size_t adjBase = (size_t)bb * NN * NN;
    const float* s2b = s2g + bb * NN;

    // precomputed per-thread geometry
    const int whF = tid >> 3;            // 0..255 (it adds 32 per step)
    const int whK = (tid & 7) * 8;       // 0..56
    const int pIr = tid >> 4;            // 0..15 (it=1 adds 16)
    const int pKq = (tid & 15) * 4;      // 0..60

    const unsigned short* whP = &WhT[whtBase + (size_t)whF * NN + whK];
    const int* adjP0 = &adj[adjBase + (size_t)(i0 + pIr) * NN + pKq];
    const int* adjP1 = adjP0 + 16 * NN;
    const float* s2P = &s2b[pKq];

    // named prefetch registers
    uint4 w0, w1, w2, w3, w4, w5, w6, w7;
    int4 am0, am1;
    float4 sv0, sv1;

#define LOAD_TILE(J0)                                                         \
    do {                                                                      \
        const int j0_ = (J0);                                                 \
        w0 = *(const uint4*)&whP[(size_t)(0 * 32) * NN + j0_];                \
        w1 = *(const uint4*)&whP[(size_t)(1 * 32) * NN + j0_];                \
        w2 = *(const uint4*)&whP[(size_t)(2 * 32) * NN + j0_];                \
        w3 = *(const uint4*)&whP[(size_t)(3 * 32) * NN + j0_];                \
        w4 = *(const uint4*)&whP[(size_t)(4 * 32) * NN + j0_];                \
        w5 = *(const uint4*)&whP[(size_t)(5 * 32) * NN + j0_];                \
        w6 = *(const uint4*)&whP[(size_t)(6 * 32) * NN + j0_];                \
        w7 = *(const uint4*)&whP[(size_t)(7 * 32) * NN + j0_];                \
        am0 = *(const int4*)&adjP0[j0_];                                      \
        am1 = *(const int4*)&adjP1[j0_];                                      \
        sv0 = *(const float4*)&s2P[j0_];                                      \
        sv1 = sv0;                                                            \
    } while (0)

    LOAD_TILE(0);

    for (int t = 0; t < NN / 64; ++t) {
        // ---- prefetched WhT -> LDS ----
        *(uint4*)&WhsT[whF + 0 * 32][whK] = w0;
        *(uint4*)&WhsT[whF + 1 * 32][whK] = w1;
        *(uint4*)&WhsT[whF + 2 * 32][whK] = w2;
        *(uint4*)&WhsT[whF + 3 * 32][whK] = w3;
        *(uint4*)&WhsT[whF + 4 * 32][whK] = w4;
        *(uint4*)&WhsT[whF + 5 * 32][whK] = w5;
        *(uint4*)&WhsT[whF + 6 * 32][whK] = w6;
        *(uint4*)&WhsT[whF + 7 * 32][whK] = w7;
        // ---- P from regs: 4 j x 2 row-groups ----
#pragma unroll
        for (int it = 0; it < 2; ++it) {
            const int ir = pIr + it * 16;
            const int4 av = it ? am1 : am0;
            const float4 s2v = it ? sv1 : sv0;
            const float s1v = s1_s[ir];
            float x0 = s1v + s2v.x, x1 = s1v + s2v.y;
            float x2 = s1v + s2v.z, x3 = s1v + s2v.w;
            x0 = x0 > 0.f ? x0 : ALPHA * x0;
            x1 = x1 > 0.f ? x1 : ALPHA * x1;
            x2 = x2 > 0.f ? x2 : ALPHA * x2;
            x3 = x3 > 0.f ? x3 : ALPHA * x3;
            const float p0 = av.x > 0 ? __expf(x0) : 0.f;
            const float p1 = av.y > 0 ? __expf(x1) : 0.f;
            const float p2 = av.z > 0 ? __expf(x2) : 0.f;
            const float p3 = av.w > 0 ? __expf(x3) : 0.f;
            uint2 pk;
            pk.x = (unsigned int)f2bf(p0) | ((unsigned int)f2bf(p1) << 16);
            pk.y = (unsigned int)f2bf(p2) | ((unsigned int)f2bf(p3) << 16);
            *(uint2*)&Pb[ir][pKq] = pk;
            float ps = (p0 + p1) + (p2 + p3);
            ps += __shfl_xor(ps, 8);
            ps += __shfl_xor(ps, 4);
            ps += __shfl_xor(ps, 2);
            ps += __shfl_xor(ps, 1);
            if ((tid & 15) == 0) l_s[ir] += ps;  // unique thread per ir
        }
        __syncthreads();
        // ---- issue next tile's loads (fly during MFMA + barrier) ----
        if (t + 1 < NN / 64) LOAD_TILE((t + 1) * 64);
        // ---- MFMA: out[32 x 64f] += P[32 x 64k] * WhsT^T ----
        const int f0 = wave * 64;
#pragma unroll
        for (int k0 = 0; k0 < 64; k0 += 32) {
            bf16x8 af[2];
#pragma unroll
            for (int m = 0; m < 2; ++m)
                af[m] = *(const bf16x8*)&Pb[m * 16 + l16][k0 + quad * 8];
#pragma unroll
            for (int nf = 0; nf < 4; ++nf) {
                const bf16x8 bfr =
                    *(const bf16x8*)&WhsT[f0 + nf * 16 + l16][k0 + quad * 8];
#pragma unroll
                for (int m = 0; m < 2; ++m)
                    acc[m][nf] = __builtin_amdgcn_mfma_f32_16x16x32_bf16(
                        af[m], bfr, acc[m][nf], 0, 0, 0);
            }
        }
        __syncthreads();
    }
#undef LOAD_TILE

    // ---- epilogue ----
    if (tid < 32) l_s[tid] = 1.0f / l_s[tid];
    __syncthreads();

    const int f0 = wave * 64;
#pragma unroll
    for (int m = 0; m < 2; ++m) {
#pragma unroll
        for (int r = 0; r < 4; ++r) {
            const int row = m * 16 + quad * 4 + r;
            const float inv = l_s[row];
#pragma unroll
            for (int nf = 0; nf < 4; ++nf) {
                out[((size_t)bb * NN + i0 + row) * NF + f0 + nf * 16 + l16] =
                    acc[m][nf][r] * inv;
            }
        }
    }
}

// ---------------------------------------------------------------------------
extern "C" void kernel_launch(void* const* d_in, const int* in_sizes, int n_in,
                              void* d_out, int out_size, void* d_ws, size_t ws_size,
                              hipStream_t stream) {
    const float* h = (const float*)d_in[0];
    const int* adj = (const int*)d_in[1];
    const float* W = (const float*)d_in[2];
    const float* a = (const float*)d_in[3];
    float* out = (float*)d_out;

    unsigned short* WhT = (unsigned short*)d_ws;  // 8.4 MB bf16, [b][f][n]
    float* s1 = (float*)((char*)d_ws + (size_t)NB * NN * NF * sizeof(unsigned short));
    float* s2 = s1 + (size_t)NB * NN;
    unsigned short* WT = (unsigned short*)(s2 + (size_t)NB * NN);  // 128 KB

    k_wt<<<dim3(64), dim3(256), 0, stream>>>(W, WT, s1, s2);
    k_wh<<<dim3((NB * NN / 64) * (NF / 64)), dim3(256), 0, stream>>>(h, WT, a, WhT, s1, s2);
    k_attn<<<dim3(NB * (NN / 32)), dim3(256), 0, stream>>>(WhT, adj, s1, s2, out);
}